// Round 4
// baseline (858.946 us; speedup 1.0000x reference)
//
#include <hip/hip_runtime.h>
#include <stdint.h>

namespace {

typedef _Float16 half2_t __attribute__((ext_vector_type(2)));
template <int N> struct IC { static constexpr int value = N; };

__device__ __forceinline__ float fdot2(uint32_t a, uint32_t b, float c) {
#if __has_builtin(__builtin_amdgcn_fdot2)
  return __builtin_amdgcn_fdot2(__builtin_bit_cast(half2_t, a),
                                __builtin_bit_cast(half2_t, b), c, false);
#else
  float d;
  asm("v_dot2_f32_f16 %0, %1, %2, %3" : "=v"(d) : "v"(a), "v"(b), "v"(c));
  return d;
#endif
}

__device__ __forceinline__ uint32_t pkrtz(float a, float b) {
  return __builtin_bit_cast(uint32_t, __builtin_amdgcn_cvt_pkrtz(a, b));
}

constexpr int IMG = 512, K = 51, PAD = 25;
constexpr int NT = 128;                  // 2 waves
constexpr int PW_PAIRS = 282;            // half2 pairs per channel row (564 cols)
constexpr int NPAIR_TOT = 3 * PW_PAIRS;  // 846
constexpr int CH_DW = 284;               // 282 pairs + 2 pad dwords (71 granules)
constexpr int ROW_DW = 3 * CH_DW;        // 852
constexpr int SLOTS = 8;                 // circular row buffer (27264 B)
constexpr int CG[4] = {0, 1, 1, 2};      // per-g pair offset: ceil(g/2)

__global__ __launch_bounds__(NT, 2)     // min 2 waves/EU -> 256-reg budget
void sepconv(const float* __restrict__ fr0, const float* __restrict__ fr2,
             const float* __restrict__ V1, const float* __restrict__ H1,
             const float* __restrict__ V2, const float* __restrict__ H2,
             float* __restrict__ out)
{
  __shared__ __align__(16) uint32_t smem[SLOTS * ROW_DW];

  const int tid = threadIdx.x;
  const int wv  = tid >> 6;         // wave id = parity class (uniform per wave)
  const int l   = tid & 63;
  const int y   = blockIdx.x;
  const int b   = blockIdx.y;
  const size_t plane = (size_t)IMG * IMG;
  const int xb  = 8 * l + 4 * wv;   // first output col of this lane

  // ---- staging precompute: 7 half2 pairs per thread per row ----
  const bool k6 = tid < (NPAIR_TOT - 6 * NT);  // tid < 78
  int sdw[7], soff0[7], soff1[7];
  #pragma unroll
  for (int k = 0; k < 7; ++k) {
    if (k < 6 || k6) {
      const int P = tid + k * NT;
      const int c = P / PW_PAIRS;
      const int p = P - c * PW_PAIRS;
      sdw[k] = c * CH_DW + p;
      const int cb = (b * 3 + c) * (int)plane;
      soff0[k] = cb + min(max(2 * p - 26, 0), IMG - 1);
      soff1[k] = cb + min(max(2 * p - 25, 0), IMG - 1);
    } else { sdw[k] = 0; soff0[k] = 0; soff1[k] = 0; }
  }

  float acc[3][4];
  #pragma unroll
  for (int c = 0; c < 3; ++c)
    #pragma unroll
    for (int g = 0; g < 4; ++g) acc[c][g] = 0.f;

  #pragma unroll 1
  for (int f = 0; f < 2; ++f) {
    const float* __restrict__ fr = f ? fr2 : fr0;
    const float* __restrict__ Vb = (f ? V2 : V1) + (size_t)b * K * plane
                                   + (size_t)y * IMG + xb;
    const float* __restrict__ Hb = (f ? H2 : H1) + (size_t)b * K * plane
                                   + (size_t)y * IMG + xb;

    auto run = [&](auto EC) {
      constexpr int E = decltype(EC)::value;
      constexpr int NREAD = 7 + E;           // b128 reads per channel

      // ---- pack H taps: hh[g][s]; g even: (h[2s-1],h[2s]), g odd: (h[2s],h[2s+1])
      uint32_t hh[4][26];
      {
        float prevv[4] = {0.f, 0.f, 0.f, 0.f};
        #pragma unroll
        for (int j = 0; j <= K; ++j) {
          float curv[4] = {0.f, 0.f, 0.f, 0.f};
          if (j < K) *(float4*)curv = *(const float4*)(Hb + (size_t)j * plane);
          #pragma unroll
          for (int g = 0; g < 4; ++g) {
            if (((j + g) & 1) == 0) {
              const int sidx = ((j + g) >> 1) - CG[g];
              if (sidx >= 0 && sidx < 26)
                hh[g][sidx] = pkrtz(prevv[g], curv[g]);
            }
            prevv[g] = curv[g];
          }
        }
      }

      float laA[7], lbA[7], laB[7], lbB[7], laC[7], lbC[7];
      auto sload = [&](int lr, float (&la)[7], float (&lb)[7]) {
        const int rb = min(max(y - PAD + lr, 0), IMG - 1) * IMG;
        #pragma unroll
        for (int k2 = 0; k2 < 7; ++k2)
          if (k2 < 6 || k6) {
            la[k2] = fr[(size_t)(soff0[k2] + rb)];
            lb[k2] = fr[(size_t)(soff1[k2] + rb)];
          }
      };
      auto swrite = [&](int slot, float (&la)[7], float (&lb)[7]) {
        #pragma unroll
        for (int k2 = 0; k2 < 7; ++k2)
          if (k2 < 6 || k6)
            smem[slot * ROW_DW + sdw[k2]] = pkrtz(la[k2], lb[k2]);
      };

      __syncthreads();                 // previous frame's LDS reads complete
      sload(0, laA, lbA); sload(1, laB, lbB); sload(2, laC, lbC);
      swrite(0, laA, lbA); swrite(1, laB, lbB); swrite(2, laC, lbC);
      sload(3, laA, lbA); sload(4, laB, lbB);      // 2-deep in flight
      float4 vA = *(const float4*)(Vb);
      float4 vB = *(const float4*)(Vb + plane);

      auto do_step = [&](int s, float (&la)[7], float (&lb)[7], float4 &v) {
        __syncthreads();               // row s visible; prior writes ordered
        if (s + 3 < K) swrite((s + 3) & 7, la, lb);   // loaded 2 steps ago
        if (s + 5 < K) sload(s + 5, la, lb);          // refill same buffer
        const float4 vu = v;
        if (s + 2 < K) v = *(const float4*)(Vb + (size_t)(s + 2) * plane);
        const float vs[4] = {vu.x, vu.y, vu.z, vu.w};

        const uint32_t* base = &smem[(s & 7) * ROW_DW];
        #pragma unroll
        for (int c = 0; c < 3; ++c) {
          const uint32_t* cb2 = base + c * CH_DW + 4 * l;
          uint32_t w[4 * NREAD];
          #pragma unroll
          for (int t = 0; t < NREAD; ++t)
            *(uint4*)&w[4 * t] = *(const uint4*)(cb2 + 4 * t);

          float r0[4] = {0.f, 0.f, 0.f, 0.f}, r1[4] = {0.f, 0.f, 0.f, 0.f};
          #pragma unroll
          for (int s2 = 0; s2 < 26; ++s2) {
            #pragma unroll
            for (int g = 0; g < 4; ++g) {
              const int u = s2 + CG[g] + 2 * E;      // compile-time
              if (s2 & 1) r1[g] = fdot2(w[u], hh[g][s2], r1[g]);
              else        r0[g] = fdot2(w[u], hh[g][s2], r0[g]);
            }
          }
          #pragma unroll
          for (int g = 0; g < 4; ++g)
            acc[c][g] = fmaf(vs[g], r0[g] + r1[g], acc[c][g]);
        }
      };

      int s = 0;
      #pragma unroll 1
      for (; s + 1 < K; s += 2) {      // parity-named buffers, static indices
        do_step(s,     laA, lbA, vA);
        do_step(s + 1, laB, lbB, vB);
      }
      do_step(s, laA, lbA, vA);        // s = 50 (even)
    };

    if (__builtin_amdgcn_readfirstlane(wv) == 0) run(IC<0>{});
    else                                         run(IC<1>{});
  }

  #pragma unroll
  for (int c = 0; c < 3; ++c) {
    float4 o;
    o.x = acc[c][0]; o.y = acc[c][1]; o.z = acc[c][2]; o.w = acc[c][3];
    *(float4*)(out + ((size_t)(b * 3 + c) * IMG + y) * IMG + xb) = o;
  }
}

} // namespace

extern "C" void kernel_launch(void* const* d_in, const int* in_sizes, int n_in,
                              void* d_out, int out_size, void* d_ws, size_t ws_size,
                              hipStream_t stream)
{
  const float* frame0 = (const float*)d_in[0];
  const float* frame2 = (const float*)d_in[1];
  const float* V1 = (const float*)d_in[2];
  const float* H1 = (const float*)d_in[3];
  const float* V2 = (const float*)d_in[4];
  const float* H2 = (const float*)d_in[5];
  float* o = (float*)d_out;

  dim3 grid(IMG, 2);
  dim3 block(NT);
  hipLaunchKernelGGL(sepconv, grid, block, 0, stream,
                     frame0, frame2, V1, H1, V2, H2, o);
}

// Round 6
// 141.946 us; speedup vs baseline: 6.0512x; 6.0512x over previous
//
#include <hip/hip_runtime.h>
#include <stdint.h>

namespace {

typedef _Float16 f16x8 __attribute__((ext_vector_type(8)));
typedef float f32x16 __attribute__((ext_vector_type(16)));

__device__ __forceinline__ uint32_t pkrtz(float a, float b) {
  return __builtin_bit_cast(uint32_t, __builtin_amdgcn_cvt_pkrtz(a, b));
}

constexpr int IMG = 512, K = 51;
constexpr int NT = 256;     // 4 waves: (group g in {0,1}) x (row parity in {0,1})
constexpr int XB = 64;      // pixels per block
constexpr int YB = 16;      // output rows per block
constexpr int FSLOTS = 52;  // frame row ring (y-25 .. y+26)
constexpr int FG = 16;      // 16B granules per channel-row = 128 f16 cols
constexpr int HP = 29;      // u32 pitch of H pair-table per x
constexpr int NQ = 6;       // K=16 chunks: t_group 0..95 covers n+j up to 81

// frame tile: [ch 3][granule 16][slot 52][8 f16]  = 39936 B
// H tables:   [buf 2][par 2][x 64][29 u32]        = 29696 B   (total 69632 B)
constexpr int FR_U16 = 3 * FG * FSLOTS * 8;
constexpr int H_U32  = 2 * 2 * 64 * HP;
constexpr int CH_B   = FG * FSLOTS * 16;   // 13312 B per channel
constexpr int GR_B   = FSLOTS * 16;        // 832 B per granule

__global__ __launch_bounds__(NT, 2)
__attribute__((amdgpu_waves_per_eu(2, 2)))
void sepconv(const float* __restrict__ fr0, const float* __restrict__ fr2,
             const float* __restrict__ V1, const float* __restrict__ H1,
             const float* __restrict__ V2, const float* __restrict__ H2,
             float* __restrict__ out)
{
  __shared__ __align__(16) uint16_t frL[FR_U16];
  __shared__ uint32_t hL[H_U32];
  uint32_t* fr32 = (uint32_t*)frL;

  const int tid = threadIdx.x;
  const int l   = tid & 63;
  const int w   = tid >> 6;
  const int g   = w & 1;       // 32-px group
  const int ypar= w >> 1;      // row parity of this wave
  const int n   = l & 31;      // pixel in group == A-row index
  const int kb  = l >> 5;      // k-half
  const int x0  = blockIdx.x * XB;
  const int y0  = blockIdx.y * YB;
  const int b   = blockIdx.z;
  const size_t plane = (size_t)IMG * IMG;
  const int xloc = 32 * g + n;

  // staging roles
  const int hx = tid & 63, hw = tid >> 6;
  const int hyy = hw >> 1, hhalf = hw & 1;
  const int p0h = 13 * hhalf;                       // H pairs p0h..p0h+12
  // steady frame staging: 2 rows x 3 ch x 64 pairs = 384 tasks
  const int rr0 = tid / 192, c0t = (tid % 192) / 64, pc0 = tid % 64;
  const bool has1 = tid < 128;
  const int t1 = tid + 256;
  const int rr1 = t1 / 192, c1t = (t1 % 192) / 64, pc1 = t1 % 64;

  // zero the H-table pad slots (idx 0 and 27 of each row); persists forever
  for (int z = tid; z < 512; z += NT) {
    int row = z & 255, ss = z >> 8;
    hL[row * HP + (ss ? 27 : 0)] = 0u;
  }

  #pragma unroll 1
  for (int f = 0; f < 2; ++f) {
    const float* __restrict__ fr = f ? fr2 : fr0;
    const float* __restrict__ Vf = (f ? V2 : V1) + (size_t)b * K * plane;
    const float* __restrict__ Hf = (f ? H2 : H1) + (size_t)b * K * plane;
    const float* __restrict__ frb = fr + (size_t)b * 3 * plane;

    __syncthreads();   // previous pass's LDS reads complete

    // ---- prologue: frame rows y0-25 .. y0+26, 128 cols (pack f16 pairs) ----
    #pragma unroll 1
    for (int it = 0; it < 39; ++it) {          // 52*3*64 = 9984 = 39*256
      int task = tid + NT * it;
      {
        int rr = task / 192, rem = task % 192, c = rem / 64, pc = rem % 64;
        int row = min(max(y0 - 25 + rr, 0), IMG - 1);
        int ca  = min(max(x0 - 25 + 2 * pc, 0), IMG - 1);
        int cb  = min(max(x0 - 25 + 2 * pc + 1, 0), IMG - 1);
        float va = frb[(size_t)c * plane + (size_t)row * IMG + ca];
        float vb = frb[(size_t)c * plane + (size_t)row * IMG + cb];
        int slot = (y0 - 25 + rr + 520) % 52;
        fr32[((c * FG + (pc >> 2)) * FSLOTS + slot) * 4 + (pc & 3)] = pkrtz(va, vb);
      }
    }
    // ---- prologue: H tables buf0 for rows y0, y0+1 ----
    {
      int yH = y0 + hyy;
      int base = (hyy * 64 + hx) * HP;
      #pragma unroll
      for (int m = 0; m < 13; ++m) {
        int p = p0h + m, j0 = 2 * p;
        float a  = Hf[(size_t)j0 * plane + (size_t)yH * IMG + x0 + hx];
        float b2 = (j0 + 1 <= 50)
                 ? Hf[(size_t)(j0 + 1) * plane + (size_t)yH * IMG + x0 + hx] : 0.f;
        hL[base + p + 1] = pkrtz(a, b2);
      }
    }
    __syncthreads();

    uint32_t hcP[13];   // carried H pairs for next superstep's tables
    uint32_t fcP[2];    // carried frame-row pairs

    #pragma unroll 1
    for (int s = 0; s < 8; ++s) {
      const int buf = s & 1;
      const int y = y0 + 2 * s;

      if (s > 0) {
        __syncthreads();
        // frame rows y+25, y+26 (loaded last superstep)
        {
          int slot0 = (y + 25 + rr0 + 520) % 52;
          fr32[((c0t * FG + (pc0 >> 2)) * FSLOTS + slot0) * 4 + (pc0 & 3)] = fcP[0];
          if (has1) {
            int slot1 = (y + 25 + rr1 + 520) % 52;
            fr32[((c1t * FG + (pc1 >> 2)) * FSLOTS + slot1) * 4 + (pc1 & 3)] = fcP[1];
          }
        }
        // H tables[buf] for rows y, y+1
        {
          int base = ((buf * 2 + hyy) * 64 + hx) * HP;
          #pragma unroll
          for (int m = 0; m < 13; ++m)
            hL[base + p0h + m + 1] = hcP[m];
        }
        __syncthreads();
      }

      const int yw = y + ypar;

      // ---- V prefetch (exactly-once ownership split across kb) ----
      const float* vb = Vf + (size_t)yw * IMG + x0 + xloc + (size_t)kb * 4 * plane;
      float v0[8], v1[16], vx[3] = {0.f, 0.f, 0.f};
      #pragma unroll
      for (int r = 0; r < 8; ++r)
        v0[r] = vb[(size_t)((r & 3) + 8 * (r >> 2)) * plane];
      #pragma unroll
      for (int r = 0; r < 16; ++r)
        v1[r] = vb[(size_t)(19 + (r & 3) + 8 * (r >> 2)) * plane];
      if (kb == 0) {
        #pragma unroll
        for (int e = 0; e < 3; ++e) vx[e] = vb[(size_t)(16 + e) * plane];
      }
      float op[3] = {0.f, 0.f, 0.f};
      if (f == 1 && l < 32) {
        #pragma unroll
        for (int c = 0; c < 3; ++c)
          op[c] = out[((size_t)(b * 3 + c) * IMG + yw) * IMG + x0 + xloc];
      }

      // ---- B fragments: banded per-pixel H (6 chunks of K=16) ----
      uint4 Bq[NQ];
      {
        const uint32_t* hrow = hL + ((buf * 2 + ypar) * 64 + xloc) * HP;
        #pragma unroll
        for (int q = 0; q < NQ; ++q) {
          int j0 = 16 * q + 8 * kb - n;   // tap of element e=0
          int pb = j0 >> 1;               // arithmetic shift: floor
          uint32_t rd[5];
          #pragma unroll
          for (int ww = 0; ww < 5; ++ww) {
            int idx = min(max(pb + ww, -1), 26) + 1;  // 0 and 27 are zero slots
            rd[ww] = hrow[idx];
          }
          uint32_t fv[4];
          #pragma unroll
          for (int v = 0; v < 4; ++v) {
            uint32_t al = (uint32_t)((((uint64_t)rd[v + 1] << 32) | rd[v]) >> 16);
            fv[v] = (n & 1) ? al : rd[v];
          }
          Bq[q] = make_uint4(fv[0], fv[1], fv[2], fv[3]);
        }
      }

      // ---- issue next-superstep carries (write lands after next barrier) ----
      if (s < 7) {
        int yH = y + 2 + hyy;
        #pragma unroll
        for (int m = 0; m < 13; ++m) {
          int p = p0h + m, j0 = 2 * p;
          float a  = Hf[(size_t)j0 * plane + (size_t)yH * IMG + x0 + hx];
          float b2 = (j0 + 1 <= 50)
                   ? Hf[(size_t)(j0 + 1) * plane + (size_t)yH * IMG + x0 + hx] : 0.f;
          hcP[m] = pkrtz(a, b2);
        }
        {
          int row = min(y + 27 + rr0, IMG - 1);
          int ca  = min(max(x0 - 25 + 2 * pc0, 0), IMG - 1);
          int cb  = min(max(x0 - 25 + 2 * pc0 + 1, 0), IMG - 1);
          fcP[0] = pkrtz(frb[(size_t)c0t * plane + (size_t)row * IMG + ca],
                         frb[(size_t)c0t * plane + (size_t)row * IMG + cb]);
          if (has1) {
            int row1 = min(y + 27 + rr1, IMG - 1);
            int ca1  = min(max(x0 - 25 + 2 * pc1, 0), IMG - 1);
            int cb1  = min(max(x0 - 25 + 2 * pc1 + 1, 0), IMG - 1);
            fcP[1] = pkrtz(frb[(size_t)c1t * plane + (size_t)row1 * IMG + ca1],
                           frb[(size_t)c1t * plane + (size_t)row1 * IMG + cb1]);
          }
        }
      }

      // ---- A-frag ring bases (mt0 rows yw-25+m, mt1 rows yw-6+m; m = n) ----
      int sA = (yw - 25 + 520) % 52;
      int sB = (yw - 6 + 520) % 52;
      int slotA = sA + n; if (slotA >= 52) slotA -= 52;
      int slotB = sB + n; if (slotB >= 52) slotB -= 52;
      const char* pA0 = (const char*)frL + (4 * g + kb) * GR_B + slotA * 16;
      const char* pA1 = (const char*)frL + (4 * g + kb) * GR_B + slotB * 16;

      float accv[3];
      #pragma unroll
      for (int c = 0; c < 3; ++c) {
        float a = 0.f;
        // mt0: i = m, owned i <= 18
        {
          f32x16 D;
          #pragma unroll
          for (int e = 0; e < 16; ++e) D[e] = 0.f;
          #pragma unroll
          for (int q = 0; q < NQ; ++q) {
            f16x8 A = *(const f16x8*)(pA0 + c * CH_B + q * (2 * GR_B));
            D = __builtin_amdgcn_mfma_f32_32x32x16_f16(
                    A, __builtin_bit_cast(f16x8, Bq[q]), D, 0, 0, 0);
          }
          #pragma unroll
          for (int r = 0; r < 8; ++r) a += v0[r] * D[r];
          if (kb == 0) a += vx[0] * D[8] + vx[1] * D[9] + vx[2] * D[10];
        }
        // mt1: i = 19 + m, all 16 regs owned
        {
          f32x16 D;
          #pragma unroll
          for (int e = 0; e < 16; ++e) D[e] = 0.f;
          #pragma unroll
          for (int q = 0; q < NQ; ++q) {
            f16x8 A = *(const f16x8*)(pA1 + c * CH_B + q * (2 * GR_B));
            D = __builtin_amdgcn_mfma_f32_32x32x16_f16(
                    A, __builtin_bit_cast(f16x8, Bq[q]), D, 0, 0, 0);
          }
          #pragma unroll
          for (int r = 0; r < 16; ++r) a += v1[r] * D[r];
        }
        accv[c] = a;
      }

      // ---- cross-kb reduce + store (RMW on frame 1) ----
      #pragma unroll
      for (int c = 0; c < 3; ++c) {
        float t = accv[c] + __shfl_xor(accv[c], 32, 64);
        if (l < 32) {
          size_t oidx = ((size_t)(b * 3 + c) * IMG + yw) * IMG + x0 + xloc;
          out[oidx] = (f == 0) ? t : (op[c] + t);
        }
      }
    }
  }
}

} // namespace

extern "C" void kernel_launch(void* const* d_in, const int* in_sizes, int n_in,
                              void* d_out, int out_size, void* d_ws, size_t ws_size,
                              hipStream_t stream)
{
  const float* frame0 = (const float*)d_in[0];
  const float* frame2 = (const float*)d_in[1];
  const float* V1 = (const float*)d_in[2];
  const float* H1 = (const float*)d_in[3];
  const float* V2 = (const float*)d_in[4];
  const float* H2 = (const float*)d_in[5];
  float* o = (float*)d_out;

  dim3 grid(IMG / XB, IMG / YB, 2);
  dim3 block(NT);
  hipLaunchKernelGGL(sepconv, grid, block, 0, stream,
                     frame0, frame2, V1, H1, V2, H2, o);
}